// Round 7
// baseline (105.777 us; speedup 1.0000x reference)
//
#include <hip/hip_runtime.h>
#include <math.h>

// StructureLoss: B=32, C=1, H=W=512, 31x31 box filter, pad 15
#define BB 32
#define HH 512
#define WW 512
#define KK 31
#define PP 15
#define HSEG 8                        // rows per block (4 waves x 2 rows)
#define SEGS (HH / HSEG)              // 64
#define NBLOCKS (BB * SEGS)           // 2048
#define NTHREADS 256
#define NXCD 8
#define CHUNK (NBLOCKS / NXCD)        // 256 blocks per XCD (4 images)

__device__ inline float wave_reduce(float v) {
    #pragma unroll
    for (int off = 32; off > 0; off >>= 1) v += __shfl_down(v, off);
    return v;
}

// 3 transcendentals/px: e=exp(-|x|), r=rcp(1+e) -> sigmoid = r or 1-r,
// log1p(e) = -log(r)
__device__ inline void accum_px(float s, float tg, float x,
                                float& aw, float& ab, float& ai, float& au) {
    const float inv = 1.0f / (float)(KK * KK);
    float pooled = s * inv;
    float weit = fmaf(5.0f, fabsf(pooled - tg), 1.0f);
    float e  = __expf(-fabsf(x));
    float rr = __builtin_amdgcn_rcpf(1.0f + e);
    float bce = fmaxf(x, 0.0f) - x * tg - __logf(rr);
    float p  = (x >= 0.0f) ? rr : (1.0f - rr);
    aw += weit;
    ab = fmaf(weit, bce, ab);
    ai = fmaf(p * tg, weit, ai);
    au = fmaf(p + tg, weit, au);
}

__device__ inline float4 ld4(const float* base, int y, int c) {
    return *(const float4*)(base + (size_t)y * WW + c);
}
// row-clamped float4 load, zeroed if row OOB
__device__ inline float4 ld4z(const float* base, int y, int c) {
    int yc = min(max(y, 0), HH - 1);
    float4 v = *(const float4*)(base + (size_t)yc * WW + c);
    if (y < 0 || y >= HH) v = make_float4(0.f, 0.f, 0.f, 0.f);
    return v;
}

// Phase 1 is split across thread halves (wave-uniform: waves 0,1 vs 2,3):
//   half 0: rows y0-15..y0+3 summed DESCENDING; the last 8 loads complete
//           V[r] = sum(y0+r-15 .. y0+3) for r=7..0 (pure LDS writes).
//   half 1: rows y0+4..y0+22; preload last 8 rows to regs (earliest issue),
//           accumulate rows 4..14, then after a barrier fold 8 LDS RMWs:
//           V[r] += sum(y0+4 .. y0+r+15).
// => per-thread loads 53 -> 27, all dwordx4 (16B/lane); two independent
// 19-deep load streams per column -> ~2x in-flight bytes (HBM-cold data:
// the harness fills flush L3 every iteration, so phase 1 runs at raw HBM
// latency and lives or dies on MLP).
__global__ __launch_bounds__(NTHREADS, 6) void structure_loss_main(
    const float* __restrict__ pred, const float* __restrict__ target,
    float* __restrict__ partials /* [NBLOCKS][4] */)
{
    __shared__ float V[HSEG][WW];     // 31-row vertical sums, 16 KB
    __shared__ float red[4 * 4];

    const int t = threadIdx.x;
    const int w = t >> 6;             // wave 0..3
    const int L = t & 63;             // lane

    // XCD-bijective swizzle: XCD x gets 4 contiguous images -> vertical
    // halos of neighboring segments hit that XCD's L2.
    const int bid     = blockIdx.x;
    const int logical = (bid & (NXCD - 1)) * CHUNK + (bid >> 3);
    const int b   = logical >> 6;          // image
    const int seg = logical & (SEGS - 1);  // 8-row segment
    const int y0  = seg * HSEG;

    const float* tb = target + (size_t)b * HH * WW;
    const float* pb = pred   + (size_t)b * HH * WW;

    const int  half = t >> 7;         // 0: waves 0,1   1: waves 2,3
    const int  cc   = 4 * (t & 127);  // 4 columns per thread
    const bool interior = (y0 >= PP) && (y0 + HSEG - 1 + PP < HH);

    float4 pre[8];
    float4 run = make_float4(0.f, 0.f, 0.f, 0.f);

    if (half == 0) {
        if (interior) {
            #pragma unroll
            for (int jj = 3; jj >= -15; --jj) {
                float4 u = ld4(tb, y0 + jj, cc);
                run.x += u.x; run.y += u.y; run.z += u.z; run.w += u.w;
                if (jj <= -8) *(float4*)&V[jj + 15][cc] = run;
            }
        } else {
            #pragma unroll
            for (int jj = 3; jj >= -15; --jj) {
                float4 u = ld4z(tb, y0 + jj, cc);
                run.x += u.x; run.y += u.y; run.z += u.z; run.w += u.w;
                if (jj <= -8) *(float4*)&V[jj + 15][cc] = run;
            }
        }
    } else {
        if (interior) {
            #pragma unroll
            for (int k = 0; k < 8; ++k) pre[k] = ld4(tb, y0 + 15 + k, cc);
            #pragma unroll
            for (int jj = 4; jj <= 14; ++jj) {
                float4 u = ld4(tb, y0 + jj, cc);
                run.x += u.x; run.y += u.y; run.z += u.z; run.w += u.w;
            }
        } else {
            #pragma unroll
            for (int k = 0; k < 8; ++k) pre[k] = ld4z(tb, y0 + 15 + k, cc);
            #pragma unroll
            for (int jj = 4; jj <= 14; ++jj) {
                float4 u = ld4z(tb, y0 + jj, cc);
                run.x += u.x; run.y += u.y; run.z += u.z; run.w += u.w;
            }
        }
    }

    __syncthreads();                  // half-0's V writes visible

    if (half == 1) {
        #pragma unroll
        for (int k = 0; k < 8; ++k) {
            run.x += pre[k].x; run.y += pre[k].y;
            run.z += pre[k].z; run.w += pre[k].w;
            float4 vv = *(const float4*)&V[k][cc];
            vv.x += run.x; vv.y += run.y; vv.z += run.z; vv.w += run.w;
            *(float4*)&V[k][cc] = vv;
        }
    }

    __syncthreads();                  // V complete

    // ---- phase 2: wave w owns rows y0+2w, y0+2w+1; lane owns cols [8L,8L+8)
    const int c0 = 8 * L;
    const int yA = y0 + 2 * w;

    // edge masks for cross-lane halo (exact zero padding at row ends)
    const float m_u1 = (L >= 1) ? 1.f : 0.f;
    const float m_u2 = (L >= 2) ? 1.f : 0.f;
    const float m_d1 = (L <= 62) ? 1.f : 0.f;
    const float m_d2 = (L <= 61) ? 1.f : 0.f;

    float aw = 0.f, ab = 0.f, ai = 0.f, au = 0.f;

    #pragma unroll
    for (int r = 0; r < 2; ++r) {
        const int y    = yA + r;
        const int vrow = 2 * w + r;
        float4 tgA = ld4(tb, y, c0), tgB = ld4(tb, y, c0 + 4);
        float4 prA = ld4(pb, y, c0), prB = ld4(pb, y, c0 + 4);
        float4 vA = *(const float4*)&V[vrow][c0];
        float4 vB = *(const float4*)&V[vrow][c0 + 4];

        // ---- horizontal 31-window via cross-lane (17 shuffles, no LDS) ----
        float own  = vA.x + vA.y + vA.z + vA.w + vB.x + vB.y + vB.z + vB.w;
        float own7 = own - vA.x;   // neighbor's cols 1..7 when shifted
        float s0 = own
                 + m_u2 * __shfl_up(own7, 2)
                 + m_u1 * __shfl_up(own, 1)
                 + m_d1 * __shfl_down(own, 1);
        // add taps: cols c0+16..c0+22 = lane L+2 elems 0..6
        float a0 = m_d2 * __shfl_down(vA.x, 2);
        float a1 = m_d2 * __shfl_down(vA.y, 2);
        float a2 = m_d2 * __shfl_down(vA.z, 2);
        float a3 = m_d2 * __shfl_down(vA.w, 2);
        float a4 = m_d2 * __shfl_down(vB.x, 2);
        float a5 = m_d2 * __shfl_down(vB.y, 2);
        float a6 = m_d2 * __shfl_down(vB.z, 2);
        // sub taps: cols c0-15..c0-9 = lane L-2 elems 1..7
        float q0 = m_u2 * __shfl_up(vA.y, 2);
        float q1 = m_u2 * __shfl_up(vA.z, 2);
        float q2 = m_u2 * __shfl_up(vA.w, 2);
        float q3 = m_u2 * __shfl_up(vB.x, 2);
        float q4 = m_u2 * __shfl_up(vB.y, 2);
        float q5 = m_u2 * __shfl_up(vB.z, 2);
        float q6 = m_u2 * __shfl_up(vB.w, 2);

        float s1 = s0 + a0 - q0;
        float s2 = s1 + a1 - q1;
        float s3 = s2 + a2 - q2;
        float s4 = s3 + a3 - q3;
        float s5 = s4 + a4 - q4;
        float s6 = s5 + a5 - q5;
        float s7 = s6 + a6 - q6;

        accum_px(s0, tgA.x, prA.x, aw, ab, ai, au);
        accum_px(s1, tgA.y, prA.y, aw, ab, ai, au);
        accum_px(s2, tgA.z, prA.z, aw, ab, ai, au);
        accum_px(s3, tgA.w, prA.w, aw, ab, ai, au);
        accum_px(s4, tgB.x, prB.x, aw, ab, ai, au);
        accum_px(s5, tgB.y, prB.y, aw, ab, ai, au);
        accum_px(s6, tgB.z, prB.z, aw, ab, ai, au);
        accum_px(s7, tgB.w, prB.w, aw, ab, ai, au);
    }

    // block reduction (single barrier pair at the very end)
    aw = wave_reduce(aw);
    ab = wave_reduce(ab);
    ai = wave_reduce(ai);
    au = wave_reduce(au);
    if (L == 0) {
        red[w * 4 + 0] = aw;
        red[w * 4 + 1] = ab;
        red[w * 4 + 2] = ai;
        red[w * 4 + 3] = au;
    }
    __syncthreads();
    if (t == 0) {
        float ww = 0.f, bc = 0.f, in = 0.f, un = 0.f;
        #pragma unroll
        for (int i = 0; i < 4; ++i) {
            ww += red[i * 4 + 0];
            bc += red[i * 4 + 1];
            in += red[i * 4 + 2];
            un += red[i * 4 + 3];
        }
        float* o = partials + (size_t)logical * 4;
        o[0] = ww; o[1] = bc; o[2] = in; o[3] = un;
    }
}

__global__ __launch_bounds__(256) void structure_loss_finalize(
    const float* __restrict__ partials, float* __restrict__ out)
{
    // partials: [2048][4]; image b owns entries [b*64, (b+1)*64)
    const int t  = threadIdx.x;      // 256 threads
    const int b  = t >> 3;           // image 0..31  (8 threads per image)
    const int i0 = (t & 7) * 8;      // 8 partial-entries per thread
    float w = 0.f, bc = 0.f, in = 0.f, un = 0.f;
    #pragma unroll
    for (int k = 0; k < 8; ++k) {
        float4 v = *(const float4*)(partials + ((size_t)(b * 64 + i0 + k)) * 4);
        w += v.x; bc += v.y; in += v.z; un += v.w;
    }
    #pragma unroll
    for (int off = 4; off > 0; off >>= 1) {
        w  += __shfl_down(w, off);
        bc += __shfl_down(bc, off);
        in += __shfl_down(in, off);
        un += __shfl_down(un, off);
    }
    __shared__ float vals[32];
    if ((t & 7) == 0) {
        float wbce = bc / w;
        float wiou = 1.0f - (in + 1.0f) / (un - in + 1.0f);
        vals[b] = wbce + wiou;
    }
    __syncthreads();
    if (t < 64) {
        float v = (t < 32) ? vals[t] : 0.0f;
        v = wave_reduce(v);
        if (t == 0) out[0] = v / (float)BB;
    }
}

extern "C" void kernel_launch(void* const* d_in, const int* in_sizes, int n_in,
                              void* d_out, int out_size, void* d_ws, size_t ws_size,
                              hipStream_t stream) {
    const float* pred   = (const float*)d_in[0];
    const float* target = (const float*)d_in[1];
    float* out      = (float*)d_out;
    float* partials = (float*)d_ws;   // NBLOCKS*4 floats = 32 KB

    structure_loss_main<<<NBLOCKS, NTHREADS, 0, stream>>>(pred, target, partials);
    structure_loss_finalize<<<1, 256, 0, stream>>>(partials, out);
}

// Round 8
// 101.607 us; speedup vs baseline: 1.0410x; 1.0410x over previous
//
#include <hip/hip_runtime.h>
#include <math.h>

// StructureLoss: B=32, C=1, H=W=512, 31x31 box filter, pad 15
#define BB 32
#define HH 512
#define WW 512
#define KK 31
#define PP 15
#define HSEG 4                        // rows per block (2 waves x 2 rows)
#define SEGS (HH / HSEG)              // 128
#define NBLOCKS (BB * SEGS)           // 4096 -> 16 wg/CU x 2 waves = 32 waves/CU
#define NTHREADS 128
#define NXCD 8
#define CHUNK (NBLOCKS / NXCD)        // 512 blocks per XCD (4 images)

__device__ inline float wave_reduce(float v) {
    #pragma unroll
    for (int off = 32; off > 0; off >>= 1) v += __shfl_down(v, off);
    return v;
}

// 3 transcendentals/px: e=exp(-|x|), r=rcp(1+e) -> sigmoid = r or 1-r,
// log1p(e) = -log(r)
__device__ inline void accum_px(float s, float tg, float x,
                                float& aw, float& ab, float& ai, float& au) {
    const float inv = 1.0f / (float)(KK * KK);
    float pooled = s * inv;
    float weit = fmaf(5.0f, fabsf(pooled - tg), 1.0f);
    float e  = __expf(-fabsf(x));
    float rr = __builtin_amdgcn_rcpf(1.0f + e);
    float bce = fmaxf(x, 0.0f) - x * tg - __logf(rr);
    float p  = (x >= 0.0f) ? rr : (1.0f - rr);
    aw += weit;
    ab = fmaf(weit, bce, ab);
    ai = fmaf(p * tg, weit, ai);
    au = fmaf(p + tg, weit, au);
}

__device__ inline float4 ld4(const float* base, int y, int c) {
    return *(const float4*)(base + (size_t)y * WW + c);
}
// row-clamped float4 load, zeroed if row OOB
__device__ inline float4 ld4z(const float* base, int y, int c) {
    int yc = min(max(y, 0), HH - 1);
    float4 v = *(const float4*)(base + (size_t)yc * WW + c);
    if (y < 0 || y >= HH) v = make_float4(0.f, 0.f, 0.f, 0.f);
    return v;
}

// Max-TLP geometry: the record (R0-R7) shows HBM BW pinned at ~2 TB/s at
// every per-thread width/MLP — the kernel is latency-bound on resident
// wave count. HSEG=4 / 128-thread blocks / grid 4096 gives 16 wg/CU x
// 2 waves = 32 waves/CU (100% ceiling). LDS 8.2 KB x 16 = 131 KB < 160.
// Live set ~45 regs fits the 64-reg tier: the allocator can chase max
// occupancy WITHOUT spilling (R1/R4/R5 lesson: never force; stay small).
__global__ __launch_bounds__(NTHREADS) void structure_loss_main(
    const float* __restrict__ pred, const float* __restrict__ target,
    float* __restrict__ partials /* [NBLOCKS][4] */)
{
    __shared__ float V[HSEG][WW];     // vertical 31-row sums, 8 KB
    __shared__ float red[2 * 4];

    const int t = threadIdx.x;
    const int w = t >> 6;             // wave 0..1
    const int L = t & 63;             // lane

    // XCD-bijective swizzle: XCD x gets 4 contiguous images -> vertical
    // halos of neighboring segments hit that XCD's L2. 4096 % 8 == 0.
    const int bid     = blockIdx.x;
    const int logical = (bid & (NXCD - 1)) * CHUNK + (bid >> 3);
    const int b   = logical >> 7;          // image   (logical / SEGS)
    const int seg = logical & (SEGS - 1);  // 4-row segment
    const int y0  = seg * HSEG;

    const float* tb = target + (size_t)b * HH * WW;
    const float* pb = pred   + (size_t)b * HH * WW;

    // ---- phase 1: cooperative vertical sums. thread owns cols 4t..4t+3
    // (128 x 4 = 512). R2-proven serial slide, bit-identical numerics:
    // ascending 31-row sum for V[0], then slide add/sub for V[1..3].
    {
        const int c = 4 * t;
        float4 run = make_float4(0.f, 0.f, 0.f, 0.f);
        if (y0 >= PP && y0 + HSEG - 1 + PP < HH) {   // interior (uniform)
            #pragma unroll
            for (int j = -PP; j <= PP; ++j) {
                float4 u = ld4(tb, y0 + j, c);
                run.x += u.x; run.y += u.y; run.z += u.z; run.w += u.w;
            }
            *(float4*)&V[0][c] = run;
            #pragma unroll
            for (int r = 1; r < HSEG; ++r) {
                float4 ad = ld4(tb, y0 + r + PP, c);
                float4 sb = ld4(tb, y0 + r - PP - 1, c);
                run.x += ad.x - sb.x; run.y += ad.y - sb.y;
                run.z += ad.z - sb.z; run.w += ad.w - sb.w;
                *(float4*)&V[r][c] = run;
            }
        } else {
            #pragma unroll
            for (int j = -PP; j <= PP; ++j) {
                float4 u = ld4z(tb, y0 + j, c);
                run.x += u.x; run.y += u.y; run.z += u.z; run.w += u.w;
            }
            *(float4*)&V[0][c] = run;
            #pragma unroll
            for (int r = 1; r < HSEG; ++r) {
                float4 ad = ld4z(tb, y0 + r + PP, c);
                float4 sb = ld4z(tb, y0 + r - PP - 1, c);
                run.x += ad.x - sb.x; run.y += ad.y - sb.y;
                run.z += ad.z - sb.z; run.w += ad.w - sb.w;
                *(float4*)&V[r][c] = run;
            }
        }
    }

    __syncthreads();

    // ---- phase 2: wave w owns rows y0+2w, y0+2w+1; lane owns cols [8L,8L+8)
    const int c0 = 8 * L;
    const int yA = y0 + 2 * w;

    // edge masks for cross-lane halo (exact zero padding at row ends)
    const float m_u1 = (L >= 1) ? 1.f : 0.f;
    const float m_u2 = (L >= 2) ? 1.f : 0.f;
    const float m_d1 = (L <= 62) ? 1.f : 0.f;
    const float m_d2 = (L <= 61) ? 1.f : 0.f;

    float aw = 0.f, ab = 0.f, ai = 0.f, au = 0.f;

    #pragma unroll
    for (int r = 0; r < 2; ++r) {
        const int y    = yA + r;
        const int vrow = 2 * w + r;
        float4 tgA = ld4(tb, y, c0), tgB = ld4(tb, y, c0 + 4);
        float4 prA = ld4(pb, y, c0), prB = ld4(pb, y, c0 + 4);
        float4 vA = *(const float4*)&V[vrow][c0];
        float4 vB = *(const float4*)&V[vrow][c0 + 4];

        // ---- horizontal 31-window via cross-lane (17 shuffles, no LDS) ----
        float own  = vA.x + vA.y + vA.z + vA.w + vB.x + vB.y + vB.z + vB.w;
        float own7 = own - vA.x;   // neighbor's cols 1..7 when shifted
        float s0 = own
                 + m_u2 * __shfl_up(own7, 2)
                 + m_u1 * __shfl_up(own, 1)
                 + m_d1 * __shfl_down(own, 1);
        // add taps: cols c0+16..c0+22 = lane L+2 elems 0..6
        float a0 = m_d2 * __shfl_down(vA.x, 2);
        float a1 = m_d2 * __shfl_down(vA.y, 2);
        float a2 = m_d2 * __shfl_down(vA.z, 2);
        float a3 = m_d2 * __shfl_down(vA.w, 2);
        float a4 = m_d2 * __shfl_down(vB.x, 2);
        float a5 = m_d2 * __shfl_down(vB.y, 2);
        float a6 = m_d2 * __shfl_down(vB.z, 2);
        // sub taps: cols c0-15..c0-9 = lane L-2 elems 1..7
        float q0 = m_u2 * __shfl_up(vA.y, 2);
        float q1 = m_u2 * __shfl_up(vA.z, 2);
        float q2 = m_u2 * __shfl_up(vA.w, 2);
        float q3 = m_u2 * __shfl_up(vB.x, 2);
        float q4 = m_u2 * __shfl_up(vB.y, 2);
        float q5 = m_u2 * __shfl_up(vB.z, 2);
        float q6 = m_u2 * __shfl_up(vB.w, 2);

        float s1 = s0 + a0 - q0;
        float s2 = s1 + a1 - q1;
        float s3 = s2 + a2 - q2;
        float s4 = s3 + a3 - q3;
        float s5 = s4 + a4 - q4;
        float s6 = s5 + a5 - q5;
        float s7 = s6 + a6 - q6;

        accum_px(s0, tgA.x, prA.x, aw, ab, ai, au);
        accum_px(s1, tgA.y, prA.y, aw, ab, ai, au);
        accum_px(s2, tgA.z, prA.z, aw, ab, ai, au);
        accum_px(s3, tgA.w, prA.w, aw, ab, ai, au);
        accum_px(s4, tgB.x, prB.x, aw, ab, ai, au);
        accum_px(s5, tgB.y, prB.y, aw, ab, ai, au);
        accum_px(s6, tgB.z, prB.z, aw, ab, ai, au);
        accum_px(s7, tgB.w, prB.w, aw, ab, ai, au);
    }

    // block reduction (single barrier pair at the very end)
    aw = wave_reduce(aw);
    ab = wave_reduce(ab);
    ai = wave_reduce(ai);
    au = wave_reduce(au);
    if (L == 0) {
        red[w * 4 + 0] = aw;
        red[w * 4 + 1] = ab;
        red[w * 4 + 2] = ai;
        red[w * 4 + 3] = au;
    }
    __syncthreads();
    if (t == 0) {
        float ww = 0.f, bc = 0.f, in = 0.f, un = 0.f;
        #pragma unroll
        for (int i = 0; i < 2; ++i) {
            ww += red[i * 4 + 0];
            bc += red[i * 4 + 1];
            in += red[i * 4 + 2];
            un += red[i * 4 + 3];
        }
        float* o = partials + (size_t)logical * 4;
        o[0] = ww; o[1] = bc; o[2] = in; o[3] = un;
    }
}

__global__ __launch_bounds__(256) void structure_loss_finalize(
    const float* __restrict__ partials, float* __restrict__ out)
{
    // partials: [4096][4]; image b owns entries [b*128, (b+1)*128)
    const int t  = threadIdx.x;      // 256 threads
    const int b  = t >> 3;           // image 0..31  (8 threads per image)
    const int i0 = (t & 7) * 16;     // 16 partial-entries per thread
    float w = 0.f, bc = 0.f, in = 0.f, un = 0.f;
    #pragma unroll
    for (int k = 0; k < 16; ++k) {
        float4 v = *(const float4*)(partials + ((size_t)(b * 128 + i0 + k)) * 4);
        w += v.x; bc += v.y; in += v.z; un += v.w;
    }
    #pragma unroll
    for (int off = 4; off > 0; off >>= 1) {
        w  += __shfl_down(w, off);
        bc += __shfl_down(bc, off);
        in += __shfl_down(in, off);
        un += __shfl_down(un, off);
    }
    __shared__ float vals[32];
    if ((t & 7) == 0) {
        float wbce = bc / w;
        float wiou = 1.0f - (in + 1.0f) / (un - in + 1.0f);
        vals[b] = wbce + wiou;
    }
    __syncthreads();
    if (t < 64) {
        float v = (t < 32) ? vals[t] : 0.0f;
        v = wave_reduce(v);
        if (t == 0) out[0] = v / (float)BB;
    }
}

extern "C" void kernel_launch(void* const* d_in, const int* in_sizes, int n_in,
                              void* d_out, int out_size, void* d_ws, size_t ws_size,
                              hipStream_t stream) {
    const float* pred   = (const float*)d_in[0];
    const float* target = (const float*)d_in[1];
    float* out      = (float*)d_out;
    float* partials = (float*)d_ws;   // NBLOCKS*4 floats = 64 KB

    structure_loss_main<<<NBLOCKS, NTHREADS, 0, stream>>>(pred, target, partials);
    structure_loss_finalize<<<1, 256, 0, stream>>>(partials, out);
}